// Round 7
// baseline (253.672 us; speedup 1.0000x reference)
//
#include <hip/hip_runtime.h>
#include <cstdint>
#include <cstddef>

// ---------------------------------------------------------------------------
// CosineDistance via exact int8 reconstruction:
//   ref's 9 bit-slice GEMMs == qx (int8) @ qw^T (int8), dequant, 1 - cos.
// R2: removed single-address atomicMax serialization.
// R3: 2-phase dbuf 128x128 -- no win (90us, MfmaUtil 15%).
// R4: 256x256 deep pipeline, vmcnt(0) -- 87us (staging scattered).
// R5: pre-blocked qx/qw images -- gemm ~75us.
// R6: counted-vmcnt ring-4 (128KB LDS, 1 block/CU) -- gemm ~74us. Schedule
//     depth does NOT move the needle at 1 block/CU.
// R7: cross-block TLP: ring-2 of 32KB buffers (64KB LDS) -> 2 blocks/CU
//     (launch_bounds(512,4)). Whole 512-block grid co-resident; other
//     block's waves cover this block's drains/barriers even if the
//     compiler inserts conservative vmcnt(0) per phase.
// ---------------------------------------------------------------------------

#define D_COLS 1024
#define M_ROWS 4096   // x rows
#define N_ROWS 8192   // weight rows

using i32x4 = __attribute__((ext_vector_type(4))) int;

__device__ __forceinline__ void gload_lds16(const void* g, void* lds) {
  __builtin_amdgcn_global_load_lds(
      (const __attribute__((address_space(1))) uint32_t*)g,
      (__attribute__((address_space(3))) uint32_t*)lds, 16, 0, 0);
}

// One block per row (x rows 0..4095, w rows 4096..12287):
// invnorm[row] = 1/||row||, rmax[row] = max|row| * invnorm. No atomics.
__global__ __launch_bounds__(256) void rownorm_kernel(
    const float* __restrict__ x, const float* __restrict__ w,
    float* __restrict__ invnorm, float* __restrict__ rmax) {
  const int row = blockIdx.x;
  const float* a = (row < M_ROWS) ? x + (size_t)row * D_COLS
                                  : w + (size_t)(row - M_ROWS) * D_COLS;
  const float4 v = ((const float4*)a)[threadIdx.x];
  float ss = v.x * v.x + v.y * v.y + v.z * v.z + v.w * v.w;
  float mx = fmaxf(fmaxf(fabsf(v.x), fabsf(v.y)), fmaxf(fabsf(v.z), fabsf(v.w)));
#pragma unroll
  for (int off = 32; off; off >>= 1) {
    ss += __shfl_down(ss, off, 64);
    mx = fmaxf(mx, __shfl_down(mx, off, 64));
  }
  __shared__ float s_ss[4], s_mx[4];
  const int wave = threadIdx.x >> 6, lane = threadIdx.x & 63;
  if (lane == 0) { s_ss[wave] = ss; s_mx[wave] = mx; }
  __syncthreads();
  if (threadIdx.x == 0) {
    float tss = (s_ss[0] + s_ss[1]) + (s_ss[2] + s_ss[3]);
    float tmx = fmaxf(fmaxf(s_mx[0], s_mx[1]), fmaxf(s_mx[2], s_mx[3]));
    float inv = 1.0f / fmaxf(sqrtf(tss), 1e-12f);
    invnorm[row] = inv;
    rmax[row] = tmx * inv;
  }
}

// Single block: scales[0] = max(rmax[0:4096]), scales[1] = max(rmax[4096:12288])
__global__ __launch_bounds__(1024) void scale_reduce_kernel(
    const float* __restrict__ rmax, float* __restrict__ scales) {
  const int t = threadIdx.x;
  float mx = 0.f, mw = 0.f;
  for (int i = t; i < M_ROWS; i += 1024) mx = fmaxf(mx, rmax[i]);
  for (int i = t; i < N_ROWS; i += 1024) mw = fmaxf(mw, rmax[M_ROWS + i]);
#pragma unroll
  for (int off = 32; off; off >>= 1) {
    mx = fmaxf(mx, __shfl_down(mx, off, 64));
    mw = fmaxf(mw, __shfl_down(mw, off, 64));
  }
  __shared__ float smx[16], smw[16];
  const int wave = t >> 6, lane = t & 63;
  if (lane == 0) { smx[wave] = mx; smw[wave] = mw; }
  __syncthreads();
  if (t == 0) {
    float a = 0.f, b = 0.f;
#pragma unroll
    for (int i = 0; i < 16; ++i) { a = fmaxf(a, smx[i]); b = fmaxf(b, smw[i]); }
    scales[0] = a;
    scales[1] = b;
  }
}

// Quantize into the blocked GEMM image:
//   img uint4 index idx = ((p*64) + cc)*256 + rr   (cc = kt*8+ck in 0..63)
//   source: row r = p*256+rr, floats [r*1024 + cc*16 .. +15]
__global__ __launch_bounds__(256) void quant_blocked_kernel(
    const float* __restrict__ a, const float* __restrict__ invnorm,
    const float* __restrict__ scale, uint4* __restrict__ img) {
  const int idx = blockIdx.x * 256 + threadIdx.x;
  const int rr = idx & 255;
  const int cc = (idx >> 8) & 63;
  const int p = idx >> 14;
  const int r = p * 256 + rr;
  const float f = invnorm[r] * (127.0f / scale[0]);
  const float4* src = (const float4*)(a + (size_t)r * D_COLS + cc * 16);
  unsigned pk[4];
#pragma unroll
  for (int q = 0; q < 4; ++q) {
    const float4 v = src[q];
    const int q0 = (int)rintf(v.x * f), q1 = (int)rintf(v.y * f);
    const int q2 = (int)rintf(v.z * f), q3 = (int)rintf(v.w * f);
    pk[q] = (unsigned)(q0 & 0xff) | ((unsigned)(q1 & 0xff) << 8) |
            ((unsigned)(q2 & 0xff) << 16) | ((unsigned)(q3 & 0xff) << 24);
  }
  img[idx] = make_uint4(pk[0], pk[1], pk[2], pk[3]);
}

// ---------------------------------------------------------------------------
// int8 GEMM, 256x256 tile, 8 waves (wr=wid>>2, wc=wid&3), 16 phases of
// BK=64 bytes, mfma_i32_16x16x64_i8 (one call per m,n per phase),
// per-wave output 128x64.
//
// Pre-blocked slabs: (panel P, kt) = 32KB at (P*8+kt)*32768, layout
// [ck 0..7][rr 0..255][16B]; phase h uses kt=h>>1, half ks=h&1
// (bytes ks*16384 .. +16383 = cks 4).
//
// LDS: ring-2 of 32KB buffers (A 16KB + B 16KB) = 64KB total -> 2 blocks/CU
// at launch_bounds(512,4). Phase h: issue HT(h+1) into buf (h+1)&1;
// s_waitcnt vmcnt(4) (h's 4 loads drained, h+1's stay in flight);
// s_barrier; 12 ds_read_b128 + 32 MFMA (setprio); s_barrier.
// Ledger: buf (h+1)&1's last reads were phase h-1, completed before h-1's
// trailing barrier; reads of buf h&1 only after vmcnt-drain + barrier.
// Cross-block TLP (2 blocks/CU) covers drains regardless of compiler waits.
// ---------------------------------------------------------------------------
__global__ __launch_bounds__(512, 4) void gemm_i8_kernel(
    const char* __restrict__ qx, const char* __restrict__ qw,
    const float* __restrict__ sx, const float* __restrict__ sw,
    float* __restrict__ out) {
  __shared__ __align__(16) char L[65536];
  const int t = threadIdx.x;
  const int wave = t >> 6, lane = t & 63;
  const int wr = wave >> 2, wc = wave & 3;
  const int rl = lane & 15, ko = lane >> 4;  // ko in 0..3: 16B K-chunk of K=64

  i32x4 acc[8][4] = {};

#define ISSUE_HT(h)                                                           \
  {                                                                           \
    const int kt_ = (h) >> 1, ks_ = (h) & 1, bb_ = (h) & 1;                   \
    const char* sa_ = qx + ((size_t)blockIdx.y * 8 + kt_) * 32768 + ks_ * 16384; \
    const char* sb_ = qw + ((size_t)blockIdx.x * 8 + kt_) * 32768 + ks_ * 16384; \
    _Pragma("unroll") for (int i_ = 0; i_ < 2; ++i_) {                        \
      gload_lds16(sa_ + wave * 2048 + i_ * 1024 + lane * 16,                  \
                  L + bb_ * 32768 + wave * 2048 + i_ * 1024);                 \
      gload_lds16(sb_ + wave * 2048 + i_ * 1024 + lane * 16,                  \
                  L + bb_ * 32768 + 16384 + wave * 2048 + i_ * 1024);         \
    }                                                                         \
  }

#define PHASE(h, VM)                                                          \
  {                                                                           \
    if ((h) + 1 < 16) ISSUE_HT((h) + 1);                                      \
    asm volatile("s_waitcnt vmcnt(" #VM ")" ::: "memory");                    \
    asm volatile("s_barrier" ::: "memory");                                   \
    const char* Ab_ = L + ((h) & 1) * 32768;                                  \
    const char* Bb_ = Ab_ + 16384;                                            \
    i32x4 bf_[4];                                                             \
    _Pragma("unroll") for (int n_ = 0; n_ < 4; ++n_)                          \
      bf_[n_] = *(const i32x4*)(Bb_ + (ko * 256 + wc * 64 + n_ * 16 + rl) * 16); \
    _Pragma("unroll") for (int qm_ = 0; qm_ < 2; ++qm_) {                     \
      i32x4 af_[4];                                                           \
      _Pragma("unroll") for (int m_ = 0; m_ < 4; ++m_)                        \
        af_[m_] = *(const i32x4*)(Ab_ +                                       \
            (ko * 256 + wr * 128 + (qm_ * 4 + m_) * 16 + rl) * 16);           \
      __builtin_amdgcn_s_setprio(1);                                          \
      _Pragma("unroll") for (int m_ = 0; m_ < 4; ++m_)                        \
        _Pragma("unroll") for (int n_ = 0; n_ < 4; ++n_)                      \
          acc[qm_ * 4 + m_][n_] = __builtin_amdgcn_mfma_i32_16x16x64_i8(      \
              af_[m_], bf_[n_], acc[qm_ * 4 + m_][n_], 0, 0, 0);              \
      __builtin_amdgcn_s_setprio(0);                                          \
    }                                                                         \
    asm volatile("s_barrier" ::: "memory");                                   \
  }

  ISSUE_HT(0);  // prologue: half-tile 0 in flight

#pragma unroll 1
  for (int h = 0; h < 15; ++h) PHASE(h, 4);
  PHASE(15, 0);
#undef PHASE
#undef ISSUE_HT

  const float cs = sx[0] * sw[0] * (1.0f / 16129.0f);  // (sx/127)*(sw/127)
  const int rowBase = blockIdx.y * 256;
  const int colBase = blockIdx.x * 256;
#pragma unroll
  for (int m = 0; m < 8; ++m) {
    const int row = rowBase + wr * 128 + m * 16 + (lane >> 4) * 4;
#pragma unroll
    for (int n = 0; n < 4; ++n) {
      const int col = colBase + wc * 64 + n * 16 + rl;
#pragma unroll
      for (int j = 0; j < 4; ++j)
        out[(size_t)(row + j) * N_ROWS + col] = 1.0f - (float)acc[m][n][j] * cs;
    }
  }
}

extern "C" void kernel_launch(void* const* d_in, const int* in_sizes, int n_in,
                              void* d_out, int out_size, void* d_ws, size_t ws_size,
                              hipStream_t stream) {
  const float* x = (const float*)d_in[0];   // [4096, 1024]
  const float* w = (const float*)d_in[1];   // [8192, 1024]
  float* out = (float*)d_out;               // [4096, 8192]

  char* ws = (char*)d_ws;
  char* qx = ws;                                        // 4 MB blocked image
  char* qw = ws + (size_t)M_ROWS * D_COLS;              // 8 MB blocked image
  float* invnorm = (float*)(ws + (size_t)(M_ROWS + N_ROWS) * D_COLS);  // [12288]
  float* rmax = invnorm + (M_ROWS + N_ROWS);            // [12288]
  float* scales = rmax + (M_ROWS + N_ROWS);             // [0]=sx, [1]=sw

  rownorm_kernel<<<M_ROWS + N_ROWS, 256, 0, stream>>>(x, w, invnorm, rmax);
  scale_reduce_kernel<<<1, 1024, 0, stream>>>(rmax, scales);

  quant_blocked_kernel<<<M_ROWS * (D_COLS / 16) / 256, 256, 0, stream>>>(
      x, invnorm, &scales[0], (uint4*)qx);
  quant_blocked_kernel<<<N_ROWS * (D_COLS / 16) / 256, 256, 0, stream>>>(
      w, invnorm + M_ROWS, &scales[1], (uint4*)qw);

  dim3 grid(N_ROWS / 256, M_ROWS / 256);  // (32, 16) = 512 blocks
  gemm_i8_kernel<<<grid, 512, 0, stream>>>(qx, qw, &scales[0], &scales[1], out);
}

// Round 8
// 96.662 us; speedup vs baseline: 2.6243x; 2.6243x over previous
//
#include <hip/hip_runtime.h>
#include <cstdint>
#include <cstddef>

// ---------------------------------------------------------------------------
// CosineDistance via exact int8 reconstruction:
//   ref's 9 bit-slice GEMMs == qx (int8) @ qw^T (int8), dequant, 1 - cos.
// R2: removed single-address atomicMax serialization.
// R3-R6: three barrier-lockstep LDS staging schedules all pin gemm ~74us
//        (all pipes <25%). R7: launch_bounds(512,4) reg-cap -> spill, 254us.
// R8: NO-LDS GEMM. Fragments loaded directly global->VGPR from the
//     pre-blocked image (each fragment load = contiguous 1KB/wave, full
//     line utilization). No barriers, no staging: compiler scoreboard +
//     unroll-2 ILP + 12 waves/CU TLP. 128x128 block of 4 waves (64x64
//     each, acc=64 regs), launch_bounds(256,3) (~170 reg cap, ~140 used).
// ---------------------------------------------------------------------------

#define D_COLS 1024
#define M_ROWS 4096   // x rows
#define N_ROWS 8192   // weight rows

using i32x4 = __attribute__((ext_vector_type(4))) int;

// One block per row (x rows 0..4095, w rows 4096..12287):
// invnorm[row] = 1/||row||, rmax[row] = max|row| * invnorm. No atomics.
__global__ __launch_bounds__(256) void rownorm_kernel(
    const float* __restrict__ x, const float* __restrict__ w,
    float* __restrict__ invnorm, float* __restrict__ rmax) {
  const int row = blockIdx.x;
  const float* a = (row < M_ROWS) ? x + (size_t)row * D_COLS
                                  : w + (size_t)(row - M_ROWS) * D_COLS;
  const float4 v = ((const float4*)a)[threadIdx.x];
  float ss = v.x * v.x + v.y * v.y + v.z * v.z + v.w * v.w;
  float mx = fmaxf(fmaxf(fabsf(v.x), fabsf(v.y)), fmaxf(fabsf(v.z), fabsf(v.w)));
#pragma unroll
  for (int off = 32; off; off >>= 1) {
    ss += __shfl_down(ss, off, 64);
    mx = fmaxf(mx, __shfl_down(mx, off, 64));
  }
  __shared__ float s_ss[4], s_mx[4];
  const int wave = threadIdx.x >> 6, lane = threadIdx.x & 63;
  if (lane == 0) { s_ss[wave] = ss; s_mx[wave] = mx; }
  __syncthreads();
  if (threadIdx.x == 0) {
    float tss = (s_ss[0] + s_ss[1]) + (s_ss[2] + s_ss[3]);
    float tmx = fmaxf(fmaxf(s_mx[0], s_mx[1]), fmaxf(s_mx[2], s_mx[3]));
    float inv = 1.0f / fmaxf(sqrtf(tss), 1e-12f);
    invnorm[row] = inv;
    rmax[row] = tmx * inv;
  }
}

// Single block: scales[0] = max(rmax[0:4096]), scales[1] = max(rmax[4096:12288])
__global__ __launch_bounds__(1024) void scale_reduce_kernel(
    const float* __restrict__ rmax, float* __restrict__ scales) {
  const int t = threadIdx.x;
  float mx = 0.f, mw = 0.f;
  for (int i = t; i < M_ROWS; i += 1024) mx = fmaxf(mx, rmax[i]);
  for (int i = t; i < N_ROWS; i += 1024) mw = fmaxf(mw, rmax[M_ROWS + i]);
#pragma unroll
  for (int off = 32; off; off >>= 1) {
    mx = fmaxf(mx, __shfl_down(mx, off, 64));
    mw = fmaxf(mw, __shfl_down(mw, off, 64));
  }
  __shared__ float smx[16], smw[16];
  const int wave = t >> 6, lane = t & 63;
  if (lane == 0) { smx[wave] = mx; smw[wave] = mw; }
  __syncthreads();
  if (t == 0) {
    float a = 0.f, b = 0.f;
#pragma unroll
    for (int i = 0; i < 16; ++i) { a = fmaxf(a, smx[i]); b = fmaxf(b, smw[i]); }
    scales[0] = a;
    scales[1] = b;
  }
}

// Quantize into the blocked GEMM image:
//   img uint4 index idx = ((p*64) + cc)*256 + rr   (cc = kt*8+ck in 0..63)
//   source: row r = p*256+rr, floats [r*1024 + cc*16 .. +15]
__global__ __launch_bounds__(256) void quant_blocked_kernel(
    const float* __restrict__ a, const float* __restrict__ invnorm,
    const float* __restrict__ scale, uint4* __restrict__ img) {
  const int idx = blockIdx.x * 256 + threadIdx.x;
  const int rr = idx & 255;
  const int cc = (idx >> 8) & 63;
  const int p = idx >> 14;
  const int r = p * 256 + rr;
  const float f = invnorm[r] * (127.0f / scale[0]);
  const float4* src = (const float4*)(a + (size_t)r * D_COLS + cc * 16);
  unsigned pk[4];
#pragma unroll
  for (int q = 0; q < 4; ++q) {
    const float4 v = src[q];
    const int q0 = (int)rintf(v.x * f), q1 = (int)rintf(v.y * f);
    const int q2 = (int)rintf(v.z * f), q3 = (int)rintf(v.w * f);
    pk[q] = (unsigned)(q0 & 0xff) | ((unsigned)(q1 & 0xff) << 8) |
            ((unsigned)(q2 & 0xff) << 16) | ((unsigned)(q3 & 0xff) << 24);
  }
  img[idx] = make_uint4(pk[0], pk[1], pk[2], pk[3]);
}

// ---------------------------------------------------------------------------
// int8 GEMM, NO LDS. 128x128 block = 4 waves (2x2), each wave 64x64 out
// (acc[4][4] i32x4 = 64 regs). K=1024 = 16 phases of K=64.
//
// Blocked image: slab (panel P=row>>8, kt) = 32KB at (P*8+kt)*32768,
// inside: byte = ck*4096 + row_in_panel*16  (ck = K-16B-chunk 0..7).
// Fragment load for mfma_i32_16x16x64_i8 A/B operand: lane l needs
// row rb+(l&15), ck ckb+(l>>4) -> per-16-lane-group 256B contiguous,
// whole wave covers 1KB with full line utilization. One dwordx4 per lane.
//
// No barriers anywhere: HW scoreboard orders loads->MFMA; unroll 2 gives
// 16 loads in flight; launch_bounds(256,3) -> 12 waves/CU TLP.
// XCD-bijective block swizzle (2048 blocks % 8 == 0).
// ---------------------------------------------------------------------------
__global__ __launch_bounds__(256, 3) void gemm_i8_kernel(
    const char* __restrict__ qx, const char* __restrict__ qw,
    const float* __restrict__ sx, const float* __restrict__ sw,
    float* __restrict__ out) {
  const int t = threadIdx.x;
  const int wave = t >> 6, lane = t & 63;
  const int wr = wave >> 1, wc = wave & 1;
  const int rl = lane & 15, ko = lane >> 4;   // frag row-in-16 / k-chunk

  // XCD swizzle: consecutive swz share the A row-panel (by), L2 locality.
  const int fid = blockIdx.x;                  // 0..2047
  const int swz = (fid & 7) * 256 + (fid >> 3);
  const int bx = swz & 63;                     // col tile 0..63
  const int by = swz >> 6;                     // row tile 0..31

  // per-lane base: slab panel + (rowbase + rl)*16, ck(=ko) * 4096
  const char* Abase = qx + (size_t)(by >> 1) * 8 * 32768 + (size_t)ko * 4096 +
                      ((by & 1) * 128 + wr * 64 + rl) * 16;
  const char* Bbase = qw + (size_t)(bx >> 1) * 8 * 32768 + (size_t)ko * 4096 +
                      ((bx & 1) * 128 + wc * 64 + rl) * 16;

  i32x4 acc[4][4] = {};

#pragma unroll 2
  for (int h = 0; h < 16; ++h) {
    // slab offset: kt = h>>1 advances slab (32KB); half (h&1) is ck+4 (16KB)
    const size_t soff = (size_t)(h >> 1) * 32768 + (size_t)(h & 1) * 16384;
    i32x4 af[4], bf[4];
#pragma unroll
    for (int m = 0; m < 4; ++m)
      af[m] = *(const i32x4*)(Abase + soff + m * 256);   // m*16 rows = 256B
#pragma unroll
    for (int n = 0; n < 4; ++n)
      bf[n] = *(const i32x4*)(Bbase + soff + n * 256);
#pragma unroll
    for (int m = 0; m < 4; ++m)
#pragma unroll
      for (int n = 0; n < 4; ++n)
        acc[m][n] = __builtin_amdgcn_mfma_i32_16x16x64_i8(
            af[m], bf[n], acc[m][n], 0, 0, 0);
  }

  const float cs = sx[0] * sw[0] * (1.0f / 16129.0f);  // (sx/127)*(sw/127)
  const int rowBase = by * 128 + wr * 64;
  const int colBase = bx * 128 + wc * 64;
#pragma unroll
  for (int m = 0; m < 4; ++m) {
    const int row = rowBase + m * 16 + ko * 4;
#pragma unroll
    for (int n = 0; n < 4; ++n) {
      const int col = colBase + n * 16 + rl;
#pragma unroll
      for (int j = 0; j < 4; ++j)
        out[(size_t)(row + j) * N_ROWS + col] = 1.0f - (float)acc[m][n][j] * cs;
    }
  }
}

extern "C" void kernel_launch(void* const* d_in, const int* in_sizes, int n_in,
                              void* d_out, int out_size, void* d_ws, size_t ws_size,
                              hipStream_t stream) {
  const float* x = (const float*)d_in[0];   // [4096, 1024]
  const float* w = (const float*)d_in[1];   // [8192, 1024]
  float* out = (float*)d_out;               // [4096, 8192]

  char* ws = (char*)d_ws;
  char* qx = ws;                                        // 4 MB blocked image
  char* qw = ws + (size_t)M_ROWS * D_COLS;              // 8 MB blocked image
  float* invnorm = (float*)(ws + (size_t)(M_ROWS + N_ROWS) * D_COLS);  // [12288]
  float* rmax = invnorm + (M_ROWS + N_ROWS);            // [12288]
  float* scales = rmax + (M_ROWS + N_ROWS);             // [0]=sx, [1]=sw

  rownorm_kernel<<<M_ROWS + N_ROWS, 256, 0, stream>>>(x, w, invnorm, rmax);
  scale_reduce_kernel<<<1, 1024, 0, stream>>>(rmax, scales);

  quant_blocked_kernel<<<M_ROWS * (D_COLS / 16) / 256, 256, 0, stream>>>(
      x, invnorm, &scales[0], (uint4*)qx);
  quant_blocked_kernel<<<N_ROWS * (D_COLS / 16) / 256, 256, 0, stream>>>(
      w, invnorm + M_ROWS, &scales[1], (uint4*)qw);

  gemm_i8_kernel<<<dim3(2048), 256, 0, stream>>>(qx, qw, &scales[0], &scales[1], out);
}

// Round 9
// 80.819 us; speedup vs baseline: 3.1388x; 1.1960x over previous
//
#include <hip/hip_runtime.h>
#include <cstdint>
#include <cstddef>

// ---------------------------------------------------------------------------
// CosineDistance via exact int8 reconstruction:
//   ref's 9 bit-slice GEMMs == qx (int8) @ qw^T (int8), dequant, 1 - cos.
// R2: removed single-address atomicMax serialization.
// R3-R7: gemm schedule experiments; best = R6 counted-vmcnt ring (kept).
// R8: no-LDS gemm regressed (2x L2 traffic).
// R9: cost-model by round-differencing: quant_blocked's 4KB-stride reads
//     cost ~25us extra. Replaced with LDS-transpose quant: coalesced 1KB
//     row reads -> XOR-swizzled int8 LDS tile -> 256B-contiguous img
//     writes. Gemm = R6 byte-for-byte.
// ---------------------------------------------------------------------------

#define D_COLS 1024
#define M_ROWS 4096   // x rows
#define N_ROWS 8192   // weight rows

using i32x4 = __attribute__((ext_vector_type(4))) int;

__device__ __forceinline__ void gload_lds16(const void* g, void* lds) {
  __builtin_amdgcn_global_load_lds(
      (const __attribute__((address_space(1))) uint32_t*)g,
      (__attribute__((address_space(3))) uint32_t*)lds, 16, 0, 0);
}

// One block per row (x rows 0..4095, w rows 4096..12287):
// invnorm[row] = 1/||row||, rmax[row] = max|row| * invnorm. No atomics.
__global__ __launch_bounds__(256) void rownorm_kernel(
    const float* __restrict__ x, const float* __restrict__ w,
    float* __restrict__ invnorm, float* __restrict__ rmax) {
  const int row = blockIdx.x;
  const float* a = (row < M_ROWS) ? x + (size_t)row * D_COLS
                                  : w + (size_t)(row - M_ROWS) * D_COLS;
  const float4 v = ((const float4*)a)[threadIdx.x];
  float ss = v.x * v.x + v.y * v.y + v.z * v.z + v.w * v.w;
  float mx = fmaxf(fmaxf(fabsf(v.x), fabsf(v.y)), fmaxf(fabsf(v.z), fabsf(v.w)));
#pragma unroll
  for (int off = 32; off; off >>= 1) {
    ss += __shfl_down(ss, off, 64);
    mx = fmaxf(mx, __shfl_down(mx, off, 64));
  }
  __shared__ float s_ss[4], s_mx[4];
  const int wave = threadIdx.x >> 6, lane = threadIdx.x & 63;
  if (lane == 0) { s_ss[wave] = ss; s_mx[wave] = mx; }
  __syncthreads();
  if (threadIdx.x == 0) {
    float tss = (s_ss[0] + s_ss[1]) + (s_ss[2] + s_ss[3]);
    float tmx = fmaxf(fmaxf(s_mx[0], s_mx[1]), fmaxf(s_mx[2], s_mx[3]));
    float inv = 1.0f / fmaxf(sqrtf(tss), 1e-12f);
    invnorm[row] = inv;
    rmax[row] = tmx * inv;
  }
}

// Single block: scales[0] = max(rmax[0:4096]), scales[1] = max(rmax[4096:12288])
__global__ __launch_bounds__(1024) void scale_reduce_kernel(
    const float* __restrict__ rmax, float* __restrict__ scales) {
  const int t = threadIdx.x;
  float mx = 0.f, mw = 0.f;
  for (int i = t; i < M_ROWS; i += 1024) mx = fmaxf(mx, rmax[i]);
  for (int i = t; i < N_ROWS; i += 1024) mw = fmaxf(mw, rmax[M_ROWS + i]);
#pragma unroll
  for (int off = 32; off; off >>= 1) {
    mx = fmaxf(mx, __shfl_down(mx, off, 64));
    mw = fmaxf(mw, __shfl_down(mw, off, 64));
  }
  __shared__ float smx[16], smw[16];
  const int wave = t >> 6, lane = t & 63;
  if (lane == 0) { smx[wave] = mx; smw[wave] = mw; }
  __syncthreads();
  if (t == 0) {
    float a = 0.f, b = 0.f;
#pragma unroll
    for (int i = 0; i < 16; ++i) { a = fmaxf(a, smx[i]); b = fmaxf(b, smw[i]); }
    scales[0] = a;
    scales[1] = b;
  }
}

// ---------------------------------------------------------------------------
// Quantize + transpose into the blocked GEMM image via LDS.
// img (uint4 units): panel p (256 rows) base p*16384; entry (cc, rr) at
// cc*256 + rr, cc = K-16B-chunk 0..63, rr = row-in-panel 0..255.
// Block: 128 rows (p, rh) x 16 cc (group g). 256 threads, LDS 32KB.
// Read phase: 8 rounds; thread t reads 64B CONTIGUOUS of row
//   rr = rc*16 + (t>>4), cols cc = g*16 + (t&15); 16 threads = 1KB run.
// LDS store [rr_local][cc_local ^ (rr_local&15)] (XOR: <=2-way banks).
// Write phase: 8 rounds; thread t writes img[(g*16 + t>>4)*256 + rh*128
//   + i*16 + (t&15)] -- 16 consecutive uint4 = 256B contiguous per group.
// ---------------------------------------------------------------------------
__global__ __launch_bounds__(256) void quant_transpose_kernel(
    const float* __restrict__ a, const float* __restrict__ invnorm,
    const float* __restrict__ scale, uint4* __restrict__ img) {
  __shared__ uint4 T[128][16];
  const int t = threadIdx.x;
  const int g = blockIdx.x & 3;        // cc group (16 cc's)
  const int rh = (blockIdx.x >> 2) & 1;  // row half of panel
  const int p = blockIdx.x >> 3;       // panel
  const float s = 127.0f / scale[0];

  const int cc_l = t & 15;             // read-phase cc within group
  const int tr = t >> 4;               // read-phase row-in-16
#pragma unroll
  for (int rc = 0; rc < 8; ++rc) {
    const int rl = rc * 16 + tr;                  // row-local 0..127
    const int r = p * 256 + rh * 128 + rl;        // global row
    const float f = invnorm[r] * s;
    const float4* src = (const float4*)(a + (size_t)r * D_COLS + (g * 16 + cc_l) * 16);
    unsigned pk[4];
#pragma unroll
    for (int q = 0; q < 4; ++q) {
      const float4 v = src[q];
      const int q0 = (int)rintf(v.x * f), q1 = (int)rintf(v.y * f);
      const int q2 = (int)rintf(v.z * f), q3 = (int)rintf(v.w * f);
      pk[q] = (unsigned)(q0 & 0xff) | ((unsigned)(q1 & 0xff) << 8) |
              ((unsigned)(q2 & 0xff) << 16) | ((unsigned)(q3 & 0xff) << 24);
    }
    T[rl][cc_l ^ (rl & 15)] = make_uint4(pk[0], pk[1], pk[2], pk[3]);
  }
  __syncthreads();

  const int cc_w = t >> 4;             // write-phase cc within group
  const int rw = t & 15;               // write-phase row-in-16
  uint4* dst = img + (size_t)p * 16384 + (size_t)(g * 16 + cc_w) * 256 + rh * 128;
#pragma unroll
  for (int i = 0; i < 8; ++i) {
    const int rl = i * 16 + rw;
    dst[rl] = T[rl][cc_w ^ (rl & 15)];
  }
}

// ---------------------------------------------------------------------------
// int8 GEMM (R6, unchanged): 256x256 tile, 8 waves, BK=128B, 8 K-tiles =
// 16 half-K-tile phases, 4-buffer LDS ring, counted vmcnt(12), 2 barriers
// per phase, setprio around MFMA. See R6 ledger comments.
// ---------------------------------------------------------------------------
__global__ __launch_bounds__(512, 2) void gemm_i8_kernel(
    const char* __restrict__ qx, const char* __restrict__ qw,
    const float* __restrict__ sx, const float* __restrict__ sw,
    float* __restrict__ out) {
  __shared__ __align__(16) char L[131072];
  const int t = threadIdx.x;
  const int wave = t >> 6, lane = t & 63;
  const int wr = wave >> 2, wc = wave & 3;
  const int rl = lane & 15, ko = lane >> 4;

  i32x4 acc[8][4] = {};

#define ISSUE_HT(h)                                                           \
  {                                                                           \
    const int kt_ = (h) >> 1, ks_ = (h) & 1, bb_ = (h) & 3;                   \
    const char* sa_ = qx + ((size_t)blockIdx.y * 8 + kt_) * 32768 + ks_ * 16384; \
    const char* sb_ = qw + ((size_t)blockIdx.x * 8 + kt_) * 32768 + ks_ * 16384; \
    _Pragma("unroll") for (int i_ = 0; i_ < 2; ++i_) {                        \
      gload_lds16(sa_ + wave * 2048 + i_ * 1024 + lane * 16,                  \
                  L + bb_ * 32768 + wave * 2048 + i_ * 1024);                 \
      gload_lds16(sb_ + wave * 2048 + i_ * 1024 + lane * 16,                  \
                  L + bb_ * 32768 + 16384 + wave * 2048 + i_ * 1024);         \
    }                                                                         \
  }

#define PHASE(h, VM)                                                          \
  {                                                                           \
    if ((h) + 3 < 16) ISSUE_HT((h) + 3);                                      \
    asm volatile("s_waitcnt vmcnt(" #VM ")" ::: "memory");                    \
    asm volatile("s_barrier" ::: "memory");                                   \
    const char* Ab_ = L + ((h) & 3) * 32768;                                  \
    const char* Bb_ = Ab_ + 16384;                                            \
    i32x4 af_[8], bf_[4];                                                     \
    _Pragma("unroll") for (int m_ = 0; m_ < 8; ++m_)                          \
      af_[m_] = *(const i32x4*)(Ab_ + (ko * 256 + wr * 128 + m_ * 16 + rl) * 16); \
    _Pragma("unroll") for (int n_ = 0; n_ < 4; ++n_)                          \
      bf_[n_] = *(const i32x4*)(Bb_ + (ko * 256 + wc * 64 + n_ * 16 + rl) * 16); \
    __builtin_amdgcn_s_setprio(1);                                            \
    _Pragma("unroll") for (int m_ = 0; m_ < 8; ++m_)                          \
      _Pragma("unroll") for (int n_ = 0; n_ < 4; ++n_)                        \
        acc[m_][n_] = __builtin_amdgcn_mfma_i32_16x16x64_i8(                  \
            af_[m_], bf_[n_], acc[m_][n_], 0, 0, 0);                          \
    __builtin_amdgcn_s_setprio(0);                                            \
    asm volatile("s_barrier" ::: "memory");                                   \
  }

  ISSUE_HT(0);
  ISSUE_HT(1);
  ISSUE_HT(2);

#pragma unroll 1
  for (int h = 0; h < 13; ++h) PHASE(h, 12);
  PHASE(13, 8);
  PHASE(14, 4);
  PHASE(15, 0);
#undef PHASE
#undef ISSUE_HT

  const float cs = sx[0] * sw[0] * (1.0f / 16129.0f);  // (sx/127)*(sw/127)
  const int rowBase = blockIdx.y * 256;
  const int colBase = blockIdx.x * 256;
#pragma unroll
  for (int m = 0; m < 8; ++m) {
    const int row = rowBase + wr * 128 + m * 16 + ko * 4;
#pragma unroll
    for (int n = 0; n < 4; ++n) {
      const int col = colBase + wc * 64 + n * 16 + rl;
#pragma unroll
      for (int j = 0; j < 4; ++j)
        out[(size_t)(row + j) * N_ROWS + col] = 1.0f - (float)acc[m][n][j] * cs;
    }
  }
}

extern "C" void kernel_launch(void* const* d_in, const int* in_sizes, int n_in,
                              void* d_out, int out_size, void* d_ws, size_t ws_size,
                              hipStream_t stream) {
  const float* x = (const float*)d_in[0];   // [4096, 1024]
  const float* w = (const float*)d_in[1];   // [8192, 1024]
  float* out = (float*)d_out;               // [4096, 8192]

  char* ws = (char*)d_ws;
  char* qx = ws;                                        // 4 MB blocked image
  char* qw = ws + (size_t)M_ROWS * D_COLS;              // 8 MB blocked image
  float* invnorm = (float*)(ws + (size_t)(M_ROWS + N_ROWS) * D_COLS);  // [12288]
  float* rmax = invnorm + (M_ROWS + N_ROWS);            // [12288]
  float* scales = rmax + (M_ROWS + N_ROWS);             // [0]=sx, [1]=sw

  rownorm_kernel<<<M_ROWS + N_ROWS, 256, 0, stream>>>(x, w, invnorm, rmax);
  scale_reduce_kernel<<<1, 1024, 0, stream>>>(rmax, scales);

  // blocks = panels*2*4: x: 16 panels -> 128 blocks; w: 32 panels -> 256.
  quant_transpose_kernel<<<M_ROWS / 256 * 8, 256, 0, stream>>>(
      x, invnorm, &scales[0], (uint4*)qx);
  quant_transpose_kernel<<<N_ROWS / 256 * 8, 256, 0, stream>>>(
      w, invnorm + M_ROWS, &scales[1], (uint4*)qw);

  dim3 grid(N_ROWS / 256, M_ROWS / 256);  // (32, 16) = 512 blocks
  gemm_i8_kernel<<<grid, 512, 0, stream>>>(qx, qw, &scales[0], &scales[1], out);
}